// Round 6
// baseline (249.761 us; speedup 1.0000x reference)
//
#include <hip/hip_runtime.h>
#include <hip/hip_bf16.h>
#include <stdint.h>

// WTA dropout: per image keep values >= k-th largest (k = ceil(N*0.1)), zero rest.
// Exact radix select. Round-6 change: fused the tiny selection kernels into the
// streaming kernels via the rocPRIM last-block ticket pattern (threadfence +
// padded ticket atomic). 3 dispatches instead of 5; selection tails overlap
// other images' streaming work.

#define IMGS    32
#define NPER    1048576             // 2^20 elements per image
#define NPER4   (NPER / 4)          // 2^18 float4 per image
#define NBINS   8192                // 13-bit stage-1 bins
#define BPI_H   32                  // blocks per image, hist kernel
#define BPI_M   64                  // blocks per image, mask kernel
#define CAP     16384               // global candidate capacity per image (~11.5k expected)
#define LCAP    2048                // per-block LDS candidate capacity (~180 expected)
#define CSTRIDE 64                  // per-image counters padded 256 B apart

__device__ __forceinline__ unsigned mapf(float f) {
    unsigned u = __float_as_uint(f);
    return (u & 0x80000000u) ? ~u : (u | 0x80000000u);   // monotonic float->uint
}

// Block-wide inclusive prefix sum over 256 values (one per thread), result in p[].
__device__ __forceinline__ void block_scan256(unsigned* p, int t, unsigned v) {
    p[t] = v;
    __syncthreads();
    #pragma unroll
    for (int off = 1; off < 256; off <<= 1) {
        unsigned u = (t >= off) ? p[t - off] : 0u;
        __syncthreads();
        p[t] += u;
        __syncthreads();
    }
}

// ---------------- K0: zero hist + tickets/counters (uint4 stores) ------------
__global__ void k_zero(uint4* __restrict__ p, int n16) {
    int i = blockIdx.x * blockDim.x + threadIdx.x;
    if (i < n16) p[i] = make_uint4(0u, 0u, 0u, 0u);
}

// ------ K1: per-image 13-bit histogram + last-block threshold scan -----------
__global__ void k_hist_scan(const float4* __restrict__ x4, unsigned* __restrict__ hist,
                            unsigned* __restrict__ done0, uint2* __restrict__ binfo,
                            unsigned k) {
    __shared__ unsigned h[NBINS];               // 32 KB
    __shared__ unsigned pre[256];
    __shared__ unsigned sticket;
    int t = threadIdx.x;
    for (int j = t; j < NBINS; j += 256) h[j] = 0u;
    __syncthreads();

    int bx = blockIdx.x;
    int img = bx >> 5;                          // BPI_H = 32
    long long base4 = (long long)img * NPER4 + (long long)(bx & 31) * 8192;
    for (int it = 0; it < 32; ++it) {
        float4 v = x4[base4 + it * 256 + t];
        atomicAdd(&h[mapf(v.x) >> 19], 1u);
        atomicAdd(&h[mapf(v.y) >> 19], 1u);
        atomicAdd(&h[mapf(v.z) >> 19], 1u);
        atomicAdd(&h[mapf(v.w) >> 19], 1u);
    }
    __syncthreads();

    unsigned* gh = hist + (long long)img * NBINS;
    for (int j = t; j < NBINS; j += 256) {
        unsigned c = h[j];
        if (c) atomicAdd(&gh[j], c);
    }
    __syncthreads();
    if (t == 0) {
        __threadfence();                        // release: merged counts visible
        sticket = atomicAdd(&done0[img * CSTRIDE], 1u);
    }
    __syncthreads();
    if (sticket != BPI_H - 1) return;

    // ---- last block for this image: threshold scan ----
    __threadfence();                            // acquire
    for (int j = t; j < NBINS; j += 256) h[j] = gh[j];   // reuse LDS
    __syncthreads();

    unsigned s = 0;
    #pragma unroll
    for (int j = 0; j < 32; ++j) s += h[t * 32 + ((j + t) & 31)];  // conflict-free
    block_scan256(pre, t, s);
    unsigned above = pre[255] - pre[t];         // mass in higher-valued chunks
    if (above < k && above + s >= k) {
        unsigned cum = above;
        for (int j = 31; j >= 0; --j) {
            unsigned v = h[t * 32 + j];
            cum += v;
            if (cum >= k) {
                binfo[img] = make_uint2((unsigned)(t * 32 + j), k - (cum - v));
                break;
            }
        }
    }
}

// ---- K2: mask + candidate collect + last-block 2-round refine + fixup -------
__global__ void k_mask_fix(const float4* __restrict__ x4, float4* __restrict__ o4,
                           const uint2* __restrict__ binfo,
                           unsigned* __restrict__ counters, unsigned* __restrict__ done1,
                           unsigned* __restrict__ candKey, unsigned* __restrict__ candIdx) {
    __shared__ union {
        struct { unsigned lkey[LCAP]; unsigned lidx[LCAP]; } m;      // 16 KB mask phase
        struct { unsigned h2[2048]; unsigned h256[256]; unsigned pre[256]; } f;
    } u;
    __shared__ unsigned lcnt, gbase, sticket;
    __shared__ unsigned sh_p11, sh_r2, sh_thr;
    int t = threadIdx.x;
    if (t == 0) lcnt = 0u;
    __syncthreads();

    int bx = blockIdx.x;
    int img = bx >> 6;                          // BPI_M = 64
    unsigned b13 = binfo[img].x;
    long long base4 = (long long)img * NPER4 + (long long)(bx & 63) * 4096;

    for (int it = 0; it < 16; ++it) {
        long long i = base4 + it * 256 + t;
        float4 v = x4[i];
        unsigned ebase = (unsigned)(i & (NPER4 - 1)) * 4u;
        float4 o;
        float* vp = &v.x;
        float* op = &o.x;
        #pragma unroll
        for (int j = 0; j < 4; ++j) {
            float c = vp[j];
            unsigned key = mapf(c);
            unsigned t13 = key >> 19;
            op[j] = (t13 >= b13) ? c : 0.0f;     // boundary bin: provisional keep
            if (t13 == b13) {
                unsigned p = atomicAdd(&lcnt, 1u);
                if (p < LCAP) { u.m.lkey[p] = key; u.m.lidx[p] = ebase + (unsigned)j; }
            }
        }
        o4[i] = o;
    }
    __syncthreads();

    unsigned n = lcnt;
    if (n > LCAP) n = LCAP;
    if (t == 0) gbase = atomicAdd(&counters[img * CSTRIDE], n);   // ONE per block
    __syncthreads();
    unsigned gb = gbase;
    long long cb = (long long)img * CAP;
    for (unsigned j = t; j < n; j += 256u) {
        unsigned pos = gb + j;
        if (pos < CAP) {
            candKey[cb + pos] = u.m.lkey[j];
            candIdx[cb + pos] = u.m.lidx[j];
        }
    }
    __syncthreads();
    if (t == 0) {
        __threadfence();                        // release: candidates visible
        sticket = atomicAdd(&done1[img * CSTRIDE], 1u);
    }
    __syncthreads();
    if (sticket != BPI_M - 1) return;

    // ---- last block for this image: 2-round refine (11b + 8b) + fixup ----
    __threadfence();                            // acquire
    unsigned cnt = counters[img * CSTRIDE];
    if (cnt > CAP) cnt = CAP;
    unsigned r = binfo[img].y;
    const unsigned* ck = candKey + cb;
    const unsigned* ci = candIdx + cb;

    for (int j = t; j < 2048; j += 256) u.f.h2[j] = 0u;
    __syncthreads();
    for (unsigned j = t; j < cnt; j += 256u)
        atomicAdd(&u.f.h2[(ck[j] & 0x7FFFFu) >> 8], 1u);
    __syncthreads();

    unsigned s = 0;
    #pragma unroll
    for (int j = 0; j < 8; ++j) s += u.f.h2[t * 8 + ((j + t) & 7)];
    block_scan256(u.f.pre, t, s);
    unsigned above = u.f.pre[255] - u.f.pre[t];
    if (above < r && above + s >= r) {
        unsigned cum = above;
        for (int j = 7; j >= 0; --j) {
            unsigned v = u.f.h2[t * 8 + j];
            cum += v;
            if (cum >= r) {
                sh_p11 = (unsigned)(t * 8 + j);
                sh_r2 = r - (cum - v);
                break;
            }
        }
    }
    __syncthreads();
    unsigned p11 = sh_p11, r2 = sh_r2;

    u.f.h256[t] = 0u;
    __syncthreads();
    for (unsigned j = t; j < cnt; j += 256u) {
        unsigned kl = ck[j] & 0x7FFFFu;         // L2-hot re-read
        if ((kl >> 8) == p11) atomicAdd(&u.f.h256[kl & 0xFFu], 1u);
    }
    __syncthreads();
    unsigned v = u.f.h256[t];
    block_scan256(u.f.pre, t, v);
    unsigned above2 = u.f.pre[255] - u.f.pre[t];
    if (above2 < r2 && above2 + v >= r2)
        sh_thr = (p11 << 8) | (unsigned)t;      // exact low-19 bits of k-th largest
    __syncthreads();
    unsigned thr = sh_thr;

    float* oi = (float*)o4 + (long long)img * NPER;
    for (unsigned j = t; j < cnt; j += 256u) {
        if ((ck[j] & 0x7FFFFu) < thr) oi[ci[j]] = 0.0f;
    }
}

extern "C" void kernel_launch(void* const* d_in, const int* in_sizes, int n_in,
                              void* d_out, int out_size, void* d_ws, size_t ws_size,
                              hipStream_t stream) {
    const float* x = (const float*)d_in[0];
    float* out = (float*)d_out;
    unsigned k = (unsigned)((NPER + 9) / 10);         // ceil(N*0.1) = 104858

    // workspace layout
    char* ws = (char*)d_ws;
    size_t histB = (size_t)IMGS * NBINS * 4;                         // 1 MB
    size_t padB  = (size_t)IMGS * CSTRIDE * 4;                       // 8 KB each
    unsigned* hist     = (unsigned*)ws;
    unsigned* counters = (unsigned*)(ws + histB);
    unsigned* done0    = (unsigned*)(ws + histB + padB);
    unsigned* done1    = (unsigned*)(ws + histB + 2 * padB);
    uint2*    binfo    = (uint2*)   (ws + histB + 3 * padB);
    unsigned* candKey  = (unsigned*)(ws + histB + 3 * padB + 1024);  // 2 MB
    unsigned* candIdx  = (unsigned*)(ws + histB + 3 * padB + 1024
                                        + (size_t)IMGS * CAP * 4);   // 2 MB

    int n16 = (int)((histB + 3 * padB) / 16);
    k_zero<<<dim3((n16 + 255) / 256), dim3(256), 0, stream>>>((uint4*)ws, n16);

    dim3 blk(256);
    k_hist_scan<<<dim3(IMGS * BPI_H), blk, 0, stream>>>((const float4*)x, hist,
                                                        done0, binfo, k);
    k_mask_fix<<<dim3(IMGS * BPI_M), blk, 0, stream>>>((const float4*)x, (float4*)out,
                                                       binfo, counters, done1,
                                                       candKey, candIdx);
}

// Round 8
// 114.010 us; speedup vs baseline: 2.1907x; 2.1907x over previous
//
#include <hip/hip_runtime.h>
#include <hip/hip_bf16.h>
#include <stdint.h>

// WTA dropout: per image keep values >= k-th largest (k = ceil(N*0.1)), zero rest.
// Exact radix select. Round-8: same as round-7 (round-5 structure + nt stores +
// pipelined hist) with the nontemporal-store compile error fixed: the builtin
// needs a native clang vector type, not HIP_vector_type<float,4>.

#define IMGS    32
#define NPER    1048576             // 2^20 elements per image
#define NPER4   (NPER / 4)          // 2^18 float4 per image
#define NBINS   8192                // 13-bit stage-1 bins
#define BPI_H   32                  // blocks per image, hist kernel
#define BPI_M   64                  // blocks per image, mask kernel
#define CAP     16384               // global candidate capacity per image (~11.5k expected)
#define LCAP    2048                // per-block LDS candidate capacity (~180 expected)
#define CSTRIDE 64                  // counters padded to 256 B apart

typedef float floatx4 __attribute__((ext_vector_type(4)));

__device__ __forceinline__ unsigned mapf(float f) {
    unsigned u = __float_as_uint(f);
    return (u & 0x80000000u) ? ~u : (u | 0x80000000u);   // monotonic float->uint
}

// Block-wide inclusive prefix sum over 256 values (one per thread), result in p[].
__device__ __forceinline__ void block_scan256(unsigned* p, int t, unsigned v) {
    p[t] = v;
    __syncthreads();
    #pragma unroll
    for (int off = 1; off < 256; off <<= 1) {
        unsigned u = (t >= off) ? p[t - off] : 0u;
        __syncthreads();
        p[t] += u;
        __syncthreads();
    }
}

// ---------------- K0: zero hist + counters (uint4 stores) --------------------
__global__ void k_zero(uint4* __restrict__ p, int n16) {
    int i = blockIdx.x * blockDim.x + threadIdx.x;
    if (i < n16) p[i] = make_uint4(0u, 0u, 0u, 0u);
}

// ---------------- K1: per-image 13-bit histogram, LDS-privatized -------------
__global__ void k_hist(const float4* __restrict__ x4, unsigned* __restrict__ hist) {
    __shared__ unsigned h[NBINS];
    int t = threadIdx.x;
    for (int j = t; j < NBINS; j += 256) h[j] = 0u;
    __syncthreads();

    int bx = blockIdx.x;
    int img = bx >> 5;                          // BPI_H = 32
    long long base4 = (long long)img * NPER4 + (long long)(bx & 31) * 8192;
    // 2-deep software pipeline for memory-level parallelism
    float4 v0 = x4[base4 + t];
    for (int it = 0; it < 31; ++it) {
        float4 v1 = x4[base4 + (it + 1) * 256 + t];
        atomicAdd(&h[mapf(v0.x) >> 19], 1u);
        atomicAdd(&h[mapf(v0.y) >> 19], 1u);
        atomicAdd(&h[mapf(v0.z) >> 19], 1u);
        atomicAdd(&h[mapf(v0.w) >> 19], 1u);
        v0 = v1;
    }
    atomicAdd(&h[mapf(v0.x) >> 19], 1u);
    atomicAdd(&h[mapf(v0.y) >> 19], 1u);
    atomicAdd(&h[mapf(v0.z) >> 19], 1u);
    atomicAdd(&h[mapf(v0.w) >> 19], 1u);
    __syncthreads();

    unsigned* gh = hist + (long long)img * NBINS;
    for (int j = t; j < NBINS; j += 256) {
        unsigned c = h[j];
        if (c) atomicAdd(&gh[j], c);
    }
}

// ------- K2: find stage-1 bin b13 + rank r within it (block-parallel) --------
__global__ void k_scan(const unsigned* __restrict__ hist, uint2* __restrict__ binfo,
                       unsigned k) {
    int img = blockIdx.x;
    const unsigned* h = hist + (long long)img * NBINS;
    __shared__ unsigned bins[NBINS];            // 32 KB copy of this image's hist
    __shared__ unsigned pre[256];
    int t = threadIdx.x;

    for (int idx = t; idx < NBINS; idx += 256) bins[idx] = h[idx];
    __syncthreads();

    // chunk t = bins [t*32, t*32+32); rotated access -> conflict-free
    unsigned s = 0;
    #pragma unroll
    for (int j = 0; j < 32; ++j) s += bins[t * 32 + ((j + t) & 31)];

    block_scan256(pre, t, s);
    unsigned total_above = pre[255] - pre[t];   // mass in higher-valued chunks
    if (total_above < k && total_above + s >= k) {
        unsigned cum = total_above;
        for (int j = 31; j >= 0; --j) {
            unsigned v = bins[t * 32 + j];
            cum += v;
            if (cum >= k) {
                binfo[img] = make_uint2((unsigned)(t * 32 + j), k - (cum - v));
                break;
            }
        }
    }
}

// -------- K3: mask pass + LDS-staged boundary-bin candidate collection -------
__global__ void k_mask(const float4* __restrict__ x4, float4* __restrict__ o4,
                       const uint2* __restrict__ binfo, unsigned* __restrict__ counters,
                       unsigned* __restrict__ candKey, unsigned* __restrict__ candIdx) {
    __shared__ unsigned lkey[LCAP];
    __shared__ unsigned lidx[LCAP];
    __shared__ unsigned lcnt;
    __shared__ unsigned gbase;
    int t = threadIdx.x;
    if (t == 0) lcnt = 0u;
    __syncthreads();

    int bx = blockIdx.x;
    int img = bx >> 6;                          // BPI_M = 64
    unsigned b13 = binfo[img].x;
    long long base4 = (long long)img * NPER4 + (long long)(bx & 63) * 4096;

    for (int it = 0; it < 16; ++it) {
        long long i = base4 + it * 256 + t;
        float4 v = x4[i];
        unsigned ebase = (unsigned)(i & (NPER4 - 1)) * 4u;
        float4 o;
        float* vp = &v.x;
        float* op = &o.x;
        #pragma unroll
        for (int j = 0; j < 4; ++j) {
            float c = vp[j];
            unsigned key = mapf(c);
            unsigned t13 = key >> 19;
            op[j] = (t13 >= b13) ? c : 0.0f;     // boundary bin: provisional keep
            if (t13 == b13) {
                unsigned p = atomicAdd(&lcnt, 1u);   // LDS atomic: cheap
                if (p < LCAP) { lkey[p] = key; lidx[p] = ebase + (unsigned)j; }
            }
        }
        // write-once stream: bypass L2 (builtin needs native clang vector type)
        floatx4 ov = { o.x, o.y, o.z, o.w };
        __builtin_nontemporal_store(ov, (floatx4*)&o4[i]);
    }
    __syncthreads();

    unsigned n = lcnt;
    if (n > LCAP) n = LCAP;
    if (t == 0) gbase = atomicAdd(&counters[img * CSTRIDE], n);  // ONE per block
    __syncthreads();
    unsigned gb = gbase;
    long long cb = (long long)img * CAP;
    for (unsigned j = t; j < n; j += 256u) {
        unsigned pos = gb + j;
        if (pos < CAP) {
            candKey[cb + pos] = lkey[j];
            candIdx[cb + pos] = lidx[j];
        }
    }
}

// ---- K4: 2-round block-parallel refine (11b then 8b) + exact fixup ----------
__global__ void k_select_fix(float* __restrict__ out,
                             const uint2* __restrict__ binfo,
                             const unsigned* __restrict__ counters,
                             const unsigned* __restrict__ candKey,
                             const unsigned* __restrict__ candIdx) {
    int img = blockIdx.x;
    __shared__ unsigned klds[CAP];              // 64 KB candidate keys (low 19 bits)
    __shared__ unsigned h2[2048];               // 8 KB: 11-bit bins
    __shared__ unsigned h256[256];
    __shared__ unsigned pre[256];
    __shared__ unsigned sh_p11, sh_r2, sh_thr;
    int t = threadIdx.x;

    unsigned cnt = counters[img * CSTRIDE];
    if (cnt > CAP) cnt = CAP;
    unsigned r = binfo[img].y;
    const unsigned* ck = candKey + (long long)img * CAP;
    const unsigned* ci = candIdx + (long long)img * CAP;

    for (int j = t; j < 2048; j += 256) h2[j] = 0u;
    __syncthreads();

    // load keys -> LDS once; round-1 histogram on bits [18:8]
    for (unsigned j = t; j < cnt; j += 256u) {
        unsigned kl = ck[j] & 0x7FFFFu;
        klds[j] = kl;
        atomicAdd(&h2[kl >> 8], 1u);
    }
    __syncthreads();

    unsigned s = 0;
    #pragma unroll
    for (int j = 0; j < 8; ++j) s += h2[t * 8 + ((j + t) & 7)];
    block_scan256(pre, t, s);
    unsigned above = pre[255] - pre[t];
    if (above < r && above + s >= r) {
        unsigned cum = above;
        for (int j = 7; j >= 0; --j) {
            unsigned v = h2[t * 8 + j];
            cum += v;
            if (cum >= r) {
                sh_p11 = (unsigned)(t * 8 + j);
                sh_r2 = r - (cum - v);
                break;
            }
        }
    }
    __syncthreads();
    unsigned p11 = sh_p11, r2 = sh_r2;

    h256[t] = 0u;
    __syncthreads();
    for (unsigned j = t; j < cnt; j += 256u) {
        unsigned kl = klds[j];
        if ((kl >> 8) == p11) atomicAdd(&h256[kl & 0xFFu], 1u);
    }
    __syncthreads();
    unsigned v = h256[t];                       // thread t owns bin t
    block_scan256(pre, t, v);
    unsigned above2 = pre[255] - pre[t];
    if (above2 < r2 && above2 + v >= r2)
        sh_thr = (p11 << 8) | (unsigned)t;      // exact low-19 bits of k-th largest
    __syncthreads();
    unsigned thr = sh_thr;

    float* oi = out + (long long)img * NPER;
    for (unsigned j = t; j < cnt; j += 256u) {
        if (klds[j] < thr) oi[ci[j]] = 0.0f;
    }
}

extern "C" void kernel_launch(void* const* d_in, const int* in_sizes, int n_in,
                              void* d_out, int out_size, void* d_ws, size_t ws_size,
                              hipStream_t stream) {
    const float* x = (const float*)d_in[0];
    float* out = (float*)d_out;
    unsigned k = (unsigned)((NPER + 9) / 10);         // ceil(N*0.1) = 104858

    // workspace layout
    char* ws = (char*)d_ws;
    size_t histB = (size_t)IMGS * NBINS * 4;                         // 1 MB
    size_t cntB  = (size_t)IMGS * CSTRIDE * 4;                       // 8 KB
    unsigned* hist     = (unsigned*)ws;
    unsigned* counters = (unsigned*)(ws + histB);
    uint2*    binfo    = (uint2*)   (ws + histB + cntB);
    unsigned* candKey  = (unsigned*)(ws + histB + cntB + 1024);      // 2 MB
    unsigned* candIdx  = (unsigned*)(ws + histB + cntB + 1024
                                        + (size_t)IMGS * CAP * 4);   // 2 MB

    // zero hist + counters with our own kernel
    int n16 = (int)((histB + cntB) / 16);
    k_zero<<<dim3((n16 + 255) / 256), dim3(256), 0, stream>>>((uint4*)ws, n16);

    dim3 blk(256);
    k_hist<<<dim3(IMGS * BPI_H), blk, 0, stream>>>((const float4*)x, hist);
    k_scan<<<dim3(IMGS), blk, 0, stream>>>(hist, binfo, k);
    k_mask<<<dim3(IMGS * BPI_M), blk, 0, stream>>>((const float4*)x, (float4*)out,
                                                   binfo, counters, candKey, candIdx);
    k_select_fix<<<dim3(IMGS), blk, 0, stream>>>(out, binfo, counters, candKey, candIdx);
}